// Round 9
// baseline (354.950 us; speedup 1.0000x reference)
//
#include <hip/hip_runtime.h>
#include <stdint.h>

typedef unsigned short u16;
typedef __bf16 bf16x8 __attribute__((ext_vector_type(8)));
typedef float f32x4 __attribute__((ext_vector_type(4)));

#define S_LEN 4096
#define D_MODEL 1024
#define NHEAD 16
#define HDIM 64

__device__ __forceinline__ u16 f2bf(float f) {
  unsigned u = __builtin_bit_cast(unsigned, f);
  u += 0x7fffu + ((u >> 16) & 1u);
  return (u16)(u >> 16);
}

// XOR swizzle of 16B units within a 128B (64 x bf16) row: unit ^= row&7
__device__ __forceinline__ int swz(int row, int col) {
  return (((col >> 3) ^ (row & 7)) << 3) | (col & 7);
}

__device__ __forceinline__ void gload16(const void* g, void* l) {
  auto gp = reinterpret_cast<__attribute__((address_space(1))) void*>(
      reinterpret_cast<uintptr_t>(g));
  auto lp = reinterpret_cast<__attribute__((address_space(3))) void*>(
      static_cast<unsigned>(reinterpret_cast<uintptr_t>(l)));
  __builtin_amdgcn_global_load_lds(gp, lp, 16, 0, 0);
}

// ---------------- fp32 -> bf16 elementwise ----------------
__global__ __launch_bounds__(256) void k_conv(const float* __restrict__ in,
                                              u16* __restrict__ out, int n) {
  int i = (blockIdx.x * 256 + threadIdx.x) * 4;
  if (i >= n) return;
  float4 v = *reinterpret_cast<const float4*>(in + i);
  ushort4 o = make_ushort4(f2bf(v.x), f2bf(v.y), f2bf(v.z), f2bf(v.w));
  *reinterpret_cast<ushort4*>(out + i) = o;
}

// ---------------- fp32 [R][C] -> bf16 [C][R] ----------------
__global__ __launch_bounds__(256) void k_transpose_conv(const float* __restrict__ in,
                                                        u16* __restrict__ out,
                                                        int R, int C) {
  __shared__ float tile[32][33];
  int c0 = blockIdx.x * 32, r0 = blockIdx.y * 32;
  int tx = threadIdx.x, ty = threadIdx.y;
#pragma unroll
  for (int j = 0; j < 4; ++j)
    tile[ty + j * 8][tx] = in[(size_t)(r0 + ty + j * 8) * C + c0 + tx];
  __syncthreads();
#pragma unroll
  for (int j = 0; j < 4; ++j)
    out[(size_t)(c0 + ty + j * 8) * R + r0 + tx] = f2bf(tile[tx][ty + j * 8]);
}

// ---------------- bf16 GEMM: C[M,N] = A[M,K] * Bt[N,K]^T + bias ----------------
// MODE 0: scatter into Q/K/Vt per-head bf16 layouts (with XOR swizzle)
// MODE 1: fp32 output, row-major
template <int MODE>
__global__ __launch_bounds__(256) void k_gemm(
    const u16* __restrict__ A, const u16* __restrict__ Bt,
    const float* __restrict__ bias, float* __restrict__ Cf,
    u16* __restrict__ Qd, u16* __restrict__ Kd, u16* __restrict__ Vtd,
    int M, int N, int K) {
  __shared__ __align__(16) u16 lds[2][2 * 128 * 32];
  const int tid = threadIdx.x;
  const int w = tid >> 6, lane = tid & 63;
  const int m0 = blockIdx.y * 128, n0 = blockIdx.x * 128;
  const u16* Atile = A + (size_t)m0 * K;
  const u16* Btile = Bt + (size_t)n0 * K;
  const int r = tid >> 2, c = (tid & 3) * 8;
  const int wm = (w >> 1) * 64, wn = (w & 1) * 64;

  f32x4 acc[4][4] = {};
  const int NT = K / 32;

  {  // stage tile 0
    const u16* ga = Atile + (size_t)r * K + c;
    const u16* gb = Btile + (size_t)r * K + c;
    u16* lb = lds[0];
    gload16(ga, lb + w * 512);
    gload16(ga + (size_t)64 * K, lb + 2048 + w * 512);
    gload16(gb, lb + 4096 + w * 512);
    gload16(gb + (size_t)64 * K, lb + 4096 + 2048 + w * 512);
  }
  int cur = 0;
  for (int t = 0; t < NT; ++t) {
    __syncthreads();
    if (t + 1 < NT) {
      const u16* ga = Atile + (size_t)r * K + (t + 1) * 32 + c;
      const u16* gb = Btile + (size_t)r * K + (t + 1) * 32 + c;
      u16* lb = lds[cur ^ 1];
      gload16(ga, lb + w * 512);
      gload16(ga + (size_t)64 * K, lb + 2048 + w * 512);
      gload16(gb, lb + 4096 + w * 512);
      gload16(gb + (size_t)64 * K, lb + 4096 + 2048 + w * 512);
    }
    const u16* lA = lds[cur];
    const u16* lB = lds[cur] + 4096;
    bf16x8 af[4], bfv[4];
#pragma unroll
    for (int mi = 0; mi < 4; ++mi)
      af[mi] = *reinterpret_cast<const bf16x8*>(
          lA + (wm + mi * 16 + (lane & 15)) * 32 + (lane >> 4) * 8);
#pragma unroll
    for (int ni = 0; ni < 4; ++ni)
      bfv[ni] = *reinterpret_cast<const bf16x8*>(
          lB + (wn + ni * 16 + (lane & 15)) * 32 + (lane >> 4) * 8);
#pragma unroll
    for (int mi = 0; mi < 4; ++mi)
#pragma unroll
      for (int ni = 0; ni < 4; ++ni)
        acc[mi][ni] = __builtin_amdgcn_mfma_f32_16x16x32_bf16(af[mi], bfv[ni],
                                                              acc[mi][ni], 0, 0, 0);
    cur ^= 1;
  }
  // epilogue
#pragma unroll
  for (int mi = 0; mi < 4; ++mi) {
#pragma unroll
    for (int ni = 0; ni < 4; ++ni) {
      int colg = n0 + wn + ni * 16 + (lane & 15);
      float bv = bias[colg];
#pragma unroll
      for (int rr = 0; rr < 4; ++rr) {
        int rowg = m0 + wm + mi * 16 + ((lane >> 4) << 2) + rr;
        float v = acc[mi][ni][rr] + bv;
        if (MODE == 1) {
          Cf[(size_t)rowg * N + colg] = v;
        } else {
          u16 b = f2bf(v);
          if (colg < D_MODEL) {
            int hh = colg >> 6, dd = colg & 63;
            Qd[((size_t)hh * S_LEN + rowg) * 64 + swz(rowg, dd)] = b;
          } else if (colg < 2 * D_MODEL) {
            int cc = colg - D_MODEL;
            int hh = cc >> 6, dd = cc & 63;
            Kd[((size_t)hh * S_LEN + rowg) * 64 + swz(rowg, dd)] = b;
          } else {
            int cc = colg - 2 * D_MODEL;
            int hh = cc >> 6, dd = cc & 63;
            int sl = rowg & 63;
            Vtd[((size_t)hh * 64 + dd) * S_LEN + (rowg & ~63) + swz(dd, sl)] = b;
          }
        }
      }
    }
  }
}

// ---------------- flash attention (causal), 64-row Q tiles ----------------
// Grid (64, 16); qt = 63 - blockIdx.x -> longest blocks dispatched FIRST
// (LPT greedy balance). 48 KB LDS -> 3 blocks/CU co-resident.
// K/V double-buffered, issue-early gload_lds. Softmax in exp2 domain.
__global__ __launch_bounds__(256) void k_flash(const u16* __restrict__ Qd,
                                               const u16* __restrict__ Kd,
                                               const u16* __restrict__ Vtd,
                                               u16* __restrict__ Ao) {
  __shared__ __align__(16) u16 Qs[64 * 64];
  __shared__ __align__(16) u16 Ks[2][64 * 64];
  __shared__ __align__(16) u16 Vs[2][64 * 64];
  __shared__ __align__(16) u16 Ps[4][16 * 64];
  const int tid = threadIdx.x, w = tid >> 6, lane = tid & 63;
  const int qt = 63 - blockIdx.x, h = blockIdx.y;
  const u16* Qh = Qd + (size_t)h * S_LEN * 64;
  const u16* Kh = Kd + (size_t)h * S_LEN * 64;
  const u16* Vh = Vtd + (size_t)h * 64 * S_LEN;
  const int r8 = tid >> 3, c8 = (tid & 7) * 8;
  // scale * log2(e): softmax computed in exp2 domain (v_exp_f32 is 2^x)
  const float scl2 = 0.125f * 1.44269504088896340736f;

  {  // prologue: stage Q tile + K/V tile 0
    const u16* gq = Qh + ((size_t)(qt * 64 + r8)) * 64 + c8;
    gload16(gq, Qs + w * 512);
    gload16(gq + 32 * 64, Qs + 2048 + w * 512);
    const u16* gk = Kh + (size_t)r8 * 64 + c8;
    gload16(gk, Ks[0] + w * 512);
    gload16(gk + 32 * 64, Ks[0] + 2048 + w * 512);
    const u16* gv = Vh + (size_t)r8 * S_LEN + c8;
    gload16(gv, Vs[0] + w * 512);
    gload16(gv + (size_t)32 * S_LEN, Vs[0] + 2048 + w * 512);
  }
  __syncthreads();

  // Q fragments are loop-invariant -> hoist to registers
  bf16x8 qa[2];
#pragma unroll
  for (int kk = 0; kk < 2; ++kk) {
    const int rq = w * 16 + (lane & 15);
    qa[kk] = *reinterpret_cast<const bf16x8*>(
        Qs + rq * 64 + swz(rq, kk * 32 + (lane >> 4) * 8));
  }

  float m_run[4], l_run[4];
  f32x4 oacc[4] = {};
#pragma unroll
  for (int rr = 0; rr < 4; ++rr) {
    m_run[rr] = -1e30f;
    l_run[rr] = 0.f;
  }

  int cur = 0;
  for (int j = 0; j <= qt; ++j) {
    // issue next tile's staging BEFORE compute (latency hides under compute)
    if (j < qt) {
      const u16* gk = Kh + ((size_t)((j + 1) * 64 + r8)) * 64 + c8;
      gload16(gk, Ks[cur ^ 1] + w * 512);
      gload16(gk + 32 * 64, Ks[cur ^ 1] + 2048 + w * 512);
      const u16* gv = Vh + (size_t)r8 * S_LEN + (j + 1) * 64 + c8;
      gload16(gv, Vs[cur ^ 1] + w * 512);
      gload16(gv + (size_t)32 * S_LEN, Vs[cur ^ 1] + 2048 + w * 512);
    }

    // S = Q K^T   (wave w owns Q rows [w*16, w*16+16))
    f32x4 sacc[4] = {};
#pragma unroll
    for (int kk = 0; kk < 2; ++kk) {
#pragma unroll
      for (int ni = 0; ni < 4; ++ni) {
        const int kvl = ni * 16 + (lane & 15);
        bf16x8 kb = *reinterpret_cast<const bf16x8*>(
            Ks[cur] + kvl * 64 + swz(kvl, kk * 32 + (lane >> 4) * 8));
        sacc[ni] = __builtin_amdgcn_mfma_f32_16x16x32_bf16(qa[kk], kb, sacc[ni], 0, 0, 0);
      }
    }

    float pvv[4][4];
#pragma unroll
    for (int ni = 0; ni < 4; ++ni)
#pragma unroll
      for (int rr = 0; rr < 4; ++rr) pvv[ni][rr] = sacc[ni][rr] * scl2;

    if (j == qt) {  // diagonal tile: causal mask (wave-uniform branch)
      const int rowb = qt * 64 + w * 16 + ((lane >> 4) << 2);
#pragma unroll
      for (int ni = 0; ni < 4; ++ni) {
        const int col = j * 64 + ni * 16 + (lane & 15);
#pragma unroll
        for (int rr = 0; rr < 4; ++rr)
          if (col > rowb + rr) pvv[ni][rr] = -1e30f;
      }
    }

    // online softmax in exp2 domain (row spread over 16 lanes)
#pragma unroll
    for (int rr = 0; rr < 4; ++rr) {
      float mx = fmaxf(fmaxf(pvv[0][rr], pvv[1][rr]), fmaxf(pvv[2][rr], pvv[3][rr]));
#pragma unroll
      for (int d = 1; d < 16; d <<= 1) mx = fmaxf(mx, __shfl_xor(mx, d));
      float mn = fmaxf(m_run[rr], mx);
      float alpha = exp2f(m_run[rr] - mn);
      m_run[rr] = mn;
      float rs = 0.f;
#pragma unroll
      for (int ni = 0; ni < 4; ++ni) {
        float p = exp2f(pvv[ni][rr] - mn);
        pvv[ni][rr] = p;
        rs += p;
      }
#pragma unroll
      for (int d = 1; d < 16; d <<= 1) rs += __shfl_xor(rs, d);
      l_run[rr] = l_run[rr] * alpha + rs;
#pragma unroll
      for (int ni = 0; ni < 4; ++ni) oacc[ni][rr] *= alpha;
    }

    // P -> LDS (per-wave private buffer; same-wave write->read, no barrier)
#pragma unroll
    for (int ni = 0; ni < 4; ++ni)
#pragma unroll
      for (int rr = 0; rr < 4; ++rr) {
        int rowl = ((lane >> 4) << 2) + rr;
        int coll = ni * 16 + (lane & 15);
        Ps[w][rowl * 64 + swz(rowl, coll)] = f2bf(pvv[ni][rr]);
      }

    // O += P V
#pragma unroll
    for (int kk = 0; kk < 2; ++kk) {
      const int pr = lane & 15;
      bf16x8 pa = *reinterpret_cast<const bf16x8*>(
          Ps[w] + pr * 64 + swz(pr, kk * 32 + (lane >> 4) * 8));
#pragma unroll
      for (int ni = 0; ni < 4; ++ni) {
        const int dd = ni * 16 + (lane & 15);
        bf16x8 vb = *reinterpret_cast<const bf16x8*>(
            Vs[cur] + dd * 64 + swz(dd, kk * 32 + (lane >> 4) * 8));
        oacc[ni] = __builtin_amdgcn_mfma_f32_16x16x32_bf16(pa, vb, oacc[ni], 0, 0, 0);
      }
    }

    __syncthreads();  // drains vmcnt (next tile landed) + all waves done with cur
    cur ^= 1;
  }

  // write attention output, merged-head layout [S][1024] bf16
#pragma unroll
  for (int rr = 0; rr < 4; ++rr) {
    float inv = 1.f / l_run[rr];
    int rowg = qt * 64 + w * 16 + ((lane >> 4) << 2) + rr;
#pragma unroll
    for (int ni = 0; ni < 4; ++ni) {
      int colg = h * 64 + ni * 16 + (lane & 15);
      Ao[(size_t)rowg * D_MODEL + colg] = f2bf(oacc[ni][rr] * inv);
    }
  }
}

extern "C" void kernel_launch(void* const* d_in, const int* in_sizes, int n_in,
                              void* d_out, int out_size, void* d_ws, size_t ws_size,
                              hipStream_t stream) {
  const float* x = (const float*)d_in[0];
  const float* Wqkv = (const float*)d_in[1];
  const float* bqkv = (const float*)d_in[2];
  const float* Wproj = (const float*)d_in[3];
  const float* bproj = (const float*)d_in[4];
  float* out = (float*)d_out;
  char* ws = (char*)d_ws;

  // Workspace map (40 MB total; aout aliases xb, which is dead after k_gemm<0>):
  u16* xb = (u16*)(ws);                            // [0,8) MB   x as bf16
  u16* aout = (u16*)(ws);                          // [0,8) MB   attn out (reuses xb)
  u16* wqkvt = (u16*)(ws + (size_t)(8 << 20));     // [8,14) MB  Wqkv^T bf16
  u16* wprojt = (u16*)(ws + (size_t)(14 << 20));   // [14,16) MB Wproj^T bf16
  u16* Qd = (u16*)(ws + (size_t)(16 << 20));       // [16,24) MB
  u16* Kd = (u16*)(ws + (size_t)(24 << 20));       // [24,32) MB
  u16* Vtd = (u16*)(ws + (size_t)(32 << 20));      // [32,40) MB

  if (ws_size < (size_t)(40 << 20)) return;  // refuse to scribble OOB

  k_conv<<<dim3(4096), dim3(256), 0, stream>>>(x, xb, S_LEN * D_MODEL);
  k_transpose_conv<<<dim3(96, 32), dim3(32, 8), 0, stream>>>(Wqkv, wqkvt, D_MODEL,
                                                             3 * D_MODEL);
  k_transpose_conv<<<dim3(32, 32), dim3(32, 8), 0, stream>>>(Wproj, wprojt, D_MODEL,
                                                             D_MODEL);
  k_gemm<0><<<dim3(24, 32), dim3(256), 0, stream>>>(xb, wqkvt, bqkv, nullptr, Qd, Kd,
                                                    Vtd, S_LEN, 3 * D_MODEL, D_MODEL);
  k_flash<<<dim3(64, 16), dim3(256), 0, stream>>>(Qd, Kd, Vtd, aout);
  k_gemm<1><<<dim3(8, 32), dim3(256), 0, stream>>>(aout, wprojt, bproj, out, nullptr,
                                                   nullptr, nullptr, S_LEN, D_MODEL,
                                                   D_MODEL);
}

// Round 11
// 272.014 us; speedup vs baseline: 1.3049x; 1.3049x over previous
//
#include <hip/hip_runtime.h>
#include <stdint.h>

typedef unsigned short u16;
typedef __bf16 bf16x8 __attribute__((ext_vector_type(8)));
typedef float f32x4 __attribute__((ext_vector_type(4)));

#define S_LEN 4096
#define D_MODEL 1024
#define NHEAD 16
#define HDIM 64

__device__ __forceinline__ u16 f2bf(float f) {
  unsigned u = __builtin_bit_cast(unsigned, f);
  u += 0x7fffu + ((u >> 16) & 1u);
  return (u16)(u >> 16);
}

// XOR swizzle of 16B units within a 128B (64 x bf16) row: unit ^= row&7
__device__ __forceinline__ int swz(int row, int col) {
  return (((col >> 3) ^ (row & 7)) << 3) | (col & 7);
}

__device__ __forceinline__ void gload16(const void* g, void* l) {
  auto gp = reinterpret_cast<__attribute__((address_space(1))) void*>(
      reinterpret_cast<uintptr_t>(g));
  auto lp = reinterpret_cast<__attribute__((address_space(3))) void*>(
      static_cast<unsigned>(reinterpret_cast<uintptr_t>(l)));
  __builtin_amdgcn_global_load_lds(gp, lp, 16, 0, 0);
}

// ---------------- fp32 -> bf16 elementwise ----------------
__global__ __launch_bounds__(256) void k_conv(const float* __restrict__ in,
                                              u16* __restrict__ out, int n) {
  int i = (blockIdx.x * 256 + threadIdx.x) * 4;
  if (i >= n) return;
  float4 v = *reinterpret_cast<const float4*>(in + i);
  ushort4 o = make_ushort4(f2bf(v.x), f2bf(v.y), f2bf(v.z), f2bf(v.w));
  *reinterpret_cast<ushort4*>(out + i) = o;
}

// ---------------- fp32 [R][C] -> bf16 [C][R] ----------------
__global__ __launch_bounds__(256) void k_transpose_conv(const float* __restrict__ in,
                                                        u16* __restrict__ out,
                                                        int R, int C) {
  __shared__ float tile[32][33];
  int c0 = blockIdx.x * 32, r0 = blockIdx.y * 32;
  int tx = threadIdx.x, ty = threadIdx.y;
#pragma unroll
  for (int j = 0; j < 4; ++j)
    tile[ty + j * 8][tx] = in[(size_t)(r0 + ty + j * 8) * C + c0 + tx];
  __syncthreads();
#pragma unroll
  for (int j = 0; j < 4; ++j)
    out[(size_t)(c0 + ty + j * 8) * R + r0 + tx] = f2bf(tile[tx][ty + j * 8]);
}

// ---------------- bf16 GEMM: C[M,N] = A[M,K] * Bt[N,K]^T + bias ----------------
// MODE 0: scatter into Q/K/Vt per-head bf16 layouts (with XOR swizzle)
// MODE 1: fp32 output, row-major
template <int MODE>
__global__ __launch_bounds__(256) void k_gemm(
    const u16* __restrict__ A, const u16* __restrict__ Bt,
    const float* __restrict__ bias, float* __restrict__ Cf,
    u16* __restrict__ Qd, u16* __restrict__ Kd, u16* __restrict__ Vtd,
    int M, int N, int K) {
  __shared__ __align__(16) u16 lds[2][2 * 128 * 32];
  const int tid = threadIdx.x;
  const int w = tid >> 6, lane = tid & 63;
  const int m0 = blockIdx.y * 128, n0 = blockIdx.x * 128;
  const u16* Atile = A + (size_t)m0 * K;
  const u16* Btile = Bt + (size_t)n0 * K;
  const int r = tid >> 2, c = (tid & 3) * 8;
  const int wm = (w >> 1) * 64, wn = (w & 1) * 64;

  f32x4 acc[4][4] = {};
  const int NT = K / 32;

  {  // stage tile 0
    const u16* ga = Atile + (size_t)r * K + c;
    const u16* gb = Btile + (size_t)r * K + c;
    u16* lb = lds[0];
    gload16(ga, lb + w * 512);
    gload16(ga + (size_t)64 * K, lb + 2048 + w * 512);
    gload16(gb, lb + 4096 + w * 512);
    gload16(gb + (size_t)64 * K, lb + 4096 + 2048 + w * 512);
  }
  int cur = 0;
  for (int t = 0; t < NT; ++t) {
    __syncthreads();
    if (t + 1 < NT) {
      const u16* ga = Atile + (size_t)r * K + (t + 1) * 32 + c;
      const u16* gb = Btile + (size_t)r * K + (t + 1) * 32 + c;
      u16* lb = lds[cur ^ 1];
      gload16(ga, lb + w * 512);
      gload16(ga + (size_t)64 * K, lb + 2048 + w * 512);
      gload16(gb, lb + 4096 + w * 512);
      gload16(gb + (size_t)64 * K, lb + 4096 + 2048 + w * 512);
    }
    const u16* lA = lds[cur];
    const u16* lB = lds[cur] + 4096;
    bf16x8 af[4], bfv[4];
#pragma unroll
    for (int mi = 0; mi < 4; ++mi)
      af[mi] = *reinterpret_cast<const bf16x8*>(
          lA + (wm + mi * 16 + (lane & 15)) * 32 + (lane >> 4) * 8);
#pragma unroll
    for (int ni = 0; ni < 4; ++ni)
      bfv[ni] = *reinterpret_cast<const bf16x8*>(
          lB + (wn + ni * 16 + (lane & 15)) * 32 + (lane >> 4) * 8);
#pragma unroll
    for (int mi = 0; mi < 4; ++mi)
#pragma unroll
      for (int ni = 0; ni < 4; ++ni)
        acc[mi][ni] = __builtin_amdgcn_mfma_f32_16x16x32_bf16(af[mi], bfv[ni],
                                                              acc[mi][ni], 0, 0, 0);
    cur ^= 1;
  }
  // epilogue
#pragma unroll
  for (int mi = 0; mi < 4; ++mi) {
#pragma unroll
    for (int ni = 0; ni < 4; ++ni) {
      int colg = n0 + wn + ni * 16 + (lane & 15);
      float bv = bias[colg];
#pragma unroll
      for (int rr = 0; rr < 4; ++rr) {
        int rowg = m0 + wm + mi * 16 + ((lane >> 4) << 2) + rr;
        float v = acc[mi][ni][rr] + bv;
        if (MODE == 1) {
          Cf[(size_t)rowg * N + colg] = v;
        } else {
          u16 b = f2bf(v);
          if (colg < D_MODEL) {
            int hh = colg >> 6, dd = colg & 63;
            Qd[((size_t)hh * S_LEN + rowg) * 64 + swz(rowg, dd)] = b;
          } else if (colg < 2 * D_MODEL) {
            int cc = colg - D_MODEL;
            int hh = cc >> 6, dd = cc & 63;
            Kd[((size_t)hh * S_LEN + rowg) * 64 + swz(rowg, dd)] = b;
          } else {
            int cc = colg - 2 * D_MODEL;
            int hh = cc >> 6, dd = cc & 63;
            int sl = rowg & 63;
            Vtd[((size_t)hh * 64 + dd) * S_LEN + (rowg & ~63) + swz(dd, sl)] = b;
          }
        }
      }
    }
  }
}

// ---------------- flash attention (causal), 64-row Q tiles ----------------
// 1D grid 1024: qt = 63 - (bid>>4), h = bid&15 -> GLOBAL longest-first dispatch
// (true LPT; round-9's 2D mapping dispatched qt=63 blocks of heads 12-15 LAST,
// creating a ~90us near-empty tail). Q loaded direct global->reg (layout already
// swizzled) -> LDS 40KB -> 4 blocks/CU. K/V double-buffered, issue-early staging.
__global__ __launch_bounds__(256) void k_flash(const u16* __restrict__ Qd,
                                               const u16* __restrict__ Kd,
                                               const u16* __restrict__ Vtd,
                                               u16* __restrict__ Ao) {
  __shared__ __align__(16) u16 Ks[2][64 * 64];
  __shared__ __align__(16) u16 Vs[2][64 * 64];
  __shared__ __align__(16) u16 Ps[4][16 * 64];
  const int tid = threadIdx.x, w = tid >> 6, lane = tid & 63;
  const int bid = blockIdx.x;
  const int qt = 63 - (bid >> 4), h = bid & 15;
  const u16* Qh = Qd + (size_t)h * S_LEN * 64;
  const u16* Kh = Kd + (size_t)h * S_LEN * 64;
  const u16* Vh = Vtd + (size_t)h * 64 * S_LEN;
  const int r8 = tid >> 3, c8 = (tid & 7) * 8;
  // scale * log2(e): softmax computed in exp2 domain (v_exp_f32 is 2^x)
  const float scl2 = 0.125f * 1.44269504088896340736f;

  {  // prologue: stage K/V tile 0
    const u16* gk = Kh + (size_t)r8 * 64 + c8;
    gload16(gk, Ks[0] + w * 512);
    gload16(gk + 32 * 64, Ks[0] + 2048 + w * 512);
    const u16* gv = Vh + (size_t)r8 * S_LEN + c8;
    gload16(gv, Vs[0] + w * 512);
    gload16(gv + (size_t)32 * S_LEN, Vs[0] + 2048 + w * 512);
  }

  // Q fragments: direct global->reg (global layout carries the same swizzle;
  // row bits >=3 don't affect swz, so swz(rq,.)==swz(rq&63,.))
  bf16x8 qa[2];
  {
    const int rq = qt * 64 + w * 16 + (lane & 15);
#pragma unroll
    for (int kk = 0; kk < 2; ++kk)
      qa[kk] = *reinterpret_cast<const bf16x8*>(
          Qh + (size_t)rq * 64 + swz(rq, kk * 32 + (lane >> 4) * 8));
  }

  float m_run[4], l_run[4];
  f32x4 oacc[4] = {};
#pragma unroll
  for (int rr = 0; rr < 4; ++rr) {
    m_run[rr] = -1e30f;
    l_run[rr] = 0.f;
  }

  __syncthreads();  // K/V tile 0 landed

  int cur = 0;
  for (int j = 0; j <= qt; ++j) {
    // issue next tile's staging BEFORE compute (latency hides under compute)
    if (j < qt) {
      const u16* gk = Kh + ((size_t)((j + 1) * 64 + r8)) * 64 + c8;
      gload16(gk, Ks[cur ^ 1] + w * 512);
      gload16(gk + 32 * 64, Ks[cur ^ 1] + 2048 + w * 512);
      const u16* gv = Vh + (size_t)r8 * S_LEN + (j + 1) * 64 + c8;
      gload16(gv, Vs[cur ^ 1] + w * 512);
      gload16(gv + (size_t)32 * S_LEN, Vs[cur ^ 1] + 2048 + w * 512);
    }

    // S = Q K^T   (wave w owns Q rows [w*16, w*16+16))
    f32x4 sacc[4] = {};
#pragma unroll
    for (int kk = 0; kk < 2; ++kk) {
#pragma unroll
      for (int ni = 0; ni < 4; ++ni) {
        const int kvl = ni * 16 + (lane & 15);
        bf16x8 kb = *reinterpret_cast<const bf16x8*>(
            Ks[cur] + kvl * 64 + swz(kvl, kk * 32 + (lane >> 4) * 8));
        sacc[ni] = __builtin_amdgcn_mfma_f32_16x16x32_bf16(qa[kk], kb, sacc[ni], 0, 0, 0);
      }
    }

    float pvv[4][4];
#pragma unroll
    for (int ni = 0; ni < 4; ++ni)
#pragma unroll
      for (int rr = 0; rr < 4; ++rr) pvv[ni][rr] = sacc[ni][rr] * scl2;

    if (j == qt) {  // diagonal tile: causal mask (wave-uniform branch)
      const int rowb = qt * 64 + w * 16 + ((lane >> 4) << 2);
#pragma unroll
      for (int ni = 0; ni < 4; ++ni) {
        const int col = j * 64 + ni * 16 + (lane & 15);
#pragma unroll
        for (int rr = 0; rr < 4; ++rr)
          if (col > rowb + rr) pvv[ni][rr] = -1e30f;
      }
    }

    // online softmax in exp2 domain (row spread over 16 lanes)
#pragma unroll
    for (int rr = 0; rr < 4; ++rr) {
      float mx = fmaxf(fmaxf(pvv[0][rr], pvv[1][rr]), fmaxf(pvv[2][rr], pvv[3][rr]));
#pragma unroll
      for (int d = 1; d < 16; d <<= 1) mx = fmaxf(mx, __shfl_xor(mx, d));
      float mn = fmaxf(m_run[rr], mx);
      float alpha = exp2f(m_run[rr] - mn);
      m_run[rr] = mn;
      float rs = 0.f;
#pragma unroll
      for (int ni = 0; ni < 4; ++ni) {
        float p = exp2f(pvv[ni][rr] - mn);
        pvv[ni][rr] = p;
        rs += p;
      }
#pragma unroll
      for (int d = 1; d < 16; d <<= 1) rs += __shfl_xor(rs, d);
      l_run[rr] = l_run[rr] * alpha + rs;
#pragma unroll
      for (int ni = 0; ni < 4; ++ni) oacc[ni][rr] *= alpha;
    }

    // P -> LDS (per-wave private buffer; same-wave write->read, no barrier)
#pragma unroll
    for (int ni = 0; ni < 4; ++ni)
#pragma unroll
      for (int rr = 0; rr < 4; ++rr) {
        int rowl = ((lane >> 4) << 2) + rr;
        int coll = ni * 16 + (lane & 15);
        Ps[w][rowl * 64 + swz(rowl, coll)] = f2bf(pvv[ni][rr]);
      }

    // O += P V
#pragma unroll
    for (int kk = 0; kk < 2; ++kk) {
      const int pr = lane & 15;
      bf16x8 pa = *reinterpret_cast<const bf16x8*>(
          Ps[w] + pr * 64 + swz(pr, kk * 32 + (lane >> 4) * 8));
#pragma unroll
      for (int ni = 0; ni < 4; ++ni) {
        const int dd = ni * 16 + (lane & 15);
        bf16x8 vb = *reinterpret_cast<const bf16x8*>(
            Vs[cur] + dd * 64 + swz(dd, kk * 32 + (lane >> 4) * 8));
        oacc[ni] = __builtin_amdgcn_mfma_f32_16x16x32_bf16(pa, vb, oacc[ni], 0, 0, 0);
      }
    }

    __syncthreads();  // drains vmcnt (next tile landed) + all waves done with cur
    cur ^= 1;
  }

  // write attention output, merged-head layout [S][1024] bf16
#pragma unroll
  for (int rr = 0; rr < 4; ++rr) {
    float inv = 1.f / l_run[rr];
    int rowg = qt * 64 + w * 16 + ((lane >> 4) << 2) + rr;
#pragma unroll
    for (int ni = 0; ni < 4; ++ni) {
      int colg = h * 64 + ni * 16 + (lane & 15);
      Ao[(size_t)rowg * D_MODEL + colg] = f2bf(oacc[ni][rr] * inv);
    }
  }
}

extern "C" void kernel_launch(void* const* d_in, const int* in_sizes, int n_in,
                              void* d_out, int out_size, void* d_ws, size_t ws_size,
                              hipStream_t stream) {
  const float* x = (const float*)d_in[0];
  const float* Wqkv = (const float*)d_in[1];
  const float* bqkv = (const float*)d_in[2];
  const float* Wproj = (const float*)d_in[3];
  const float* bproj = (const float*)d_in[4];
  float* out = (float*)d_out;
  char* ws = (char*)d_ws;

  // Workspace map (40 MB total; aout aliases xb, which is dead after k_gemm<0>):
  u16* xb = (u16*)(ws);                            // [0,8) MB   x as bf16
  u16* aout = (u16*)(ws);                          // [0,8) MB   attn out (reuses xb)
  u16* wqkvt = (u16*)(ws + (size_t)(8 << 20));     // [8,14) MB  Wqkv^T bf16
  u16* wprojt = (u16*)(ws + (size_t)(14 << 20));   // [14,16) MB Wproj^T bf16
  u16* Qd = (u16*)(ws + (size_t)(16 << 20));       // [16,24) MB
  u16* Kd = (u16*)(ws + (size_t)(24 << 20));       // [24,32) MB
  u16* Vtd = (u16*)(ws + (size_t)(32 << 20));      // [32,40) MB

  if (ws_size < (size_t)(40 << 20)) return;  // refuse to scribble OOB

  k_conv<<<dim3(4096), dim3(256), 0, stream>>>(x, xb, S_LEN * D_MODEL);
  k_transpose_conv<<<dim3(96, 32), dim3(32, 8), 0, stream>>>(Wqkv, wqkvt, D_MODEL,
                                                             3 * D_MODEL);
  k_transpose_conv<<<dim3(32, 32), dim3(32, 8), 0, stream>>>(Wproj, wprojt, D_MODEL,
                                                             D_MODEL);
  k_gemm<0><<<dim3(24, 32), dim3(256), 0, stream>>>(xb, wqkvt, bqkv, nullptr, Qd, Kd,
                                                    Vtd, S_LEN, 3 * D_MODEL, D_MODEL);
  k_flash<<<dim3(1024), dim3(256), 0, stream>>>(Qd, Kd, Vtd, aout);
  k_gemm<1><<<dim3(8, 32), dim3(256), 0, stream>>>(aout, wprojt, bproj, out, nullptr,
                                                   nullptr, nullptr, S_LEN, D_MODEL,
                                                   D_MODEL);
}

// Round 12
// 252.934 us; speedup vs baseline: 1.4033x; 1.0754x over previous
//
#include <hip/hip_runtime.h>
#include <stdint.h>

typedef unsigned short u16;
typedef __bf16 bf16x8 __attribute__((ext_vector_type(8)));
typedef float f32x4 __attribute__((ext_vector_type(4)));

#define S_LEN 4096
#define D_MODEL 1024
#define NHEAD 16
#define HDIM 64

__device__ __forceinline__ u16 f2bf(float f) {
  unsigned u = __builtin_bit_cast(unsigned, f);
  u += 0x7fffu + ((u >> 16) & 1u);
  return (u16)(u >> 16);
}

// XOR swizzle of 16B units within a 128B (64 x bf16) row: unit ^= row&7
__device__ __forceinline__ int swz(int row, int col) {
  return (((col >> 3) ^ (row & 7)) << 3) | (col & 7);
}

__device__ __forceinline__ void gload16(const void* g, void* l) {
  auto gp = reinterpret_cast<__attribute__((address_space(1))) void*>(
      reinterpret_cast<uintptr_t>(g));
  auto lp = reinterpret_cast<__attribute__((address_space(3))) void*>(
      static_cast<unsigned>(reinterpret_cast<uintptr_t>(l)));
  __builtin_amdgcn_global_load_lds(gp, lp, 16, 0, 0);
}

// ---------------- fp32 -> bf16 elementwise ----------------
__global__ __launch_bounds__(256) void k_conv(const float* __restrict__ in,
                                              u16* __restrict__ out, int n) {
  int i = (blockIdx.x * 256 + threadIdx.x) * 4;
  if (i >= n) return;
  float4 v = *reinterpret_cast<const float4*>(in + i);
  ushort4 o = make_ushort4(f2bf(v.x), f2bf(v.y), f2bf(v.z), f2bf(v.w));
  *reinterpret_cast<ushort4*>(out + i) = o;
}

// ---------------- fp32 [R][C] -> bf16 [C][R] ----------------
__global__ __launch_bounds__(256) void k_transpose_conv(const float* __restrict__ in,
                                                        u16* __restrict__ out,
                                                        int R, int C) {
  __shared__ float tile[32][33];
  int c0 = blockIdx.x * 32, r0 = blockIdx.y * 32;
  int tx = threadIdx.x, ty = threadIdx.y;
#pragma unroll
  for (int j = 0; j < 4; ++j)
    tile[ty + j * 8][tx] = in[(size_t)(r0 + ty + j * 8) * C + c0 + tx];
  __syncthreads();
#pragma unroll
  for (int j = 0; j < 4; ++j)
    out[(size_t)(c0 + ty + j * 8) * R + r0 + tx] = f2bf(tile[tx][ty + j * 8]);
}

// ---------------- bf16 GEMM: C[M,N] = A[M,K] * Bt[N,K]^T + bias ----------------
// MODE 0: scatter into Q/K/Vt per-head bf16 layouts (with XOR swizzle).
//         Q is PRE-SCALED by 0.125*log2(e) so flash softmax runs in exp2
//         domain with no per-score multiply.
// MODE 1: fp32 output, row-major
template <int MODE>
__global__ __launch_bounds__(256) void k_gemm(
    const u16* __restrict__ A, const u16* __restrict__ Bt,
    const float* __restrict__ bias, float* __restrict__ Cf,
    u16* __restrict__ Qd, u16* __restrict__ Kd, u16* __restrict__ Vtd,
    int M, int N, int K) {
  __shared__ __align__(16) u16 lds[2][2 * 128 * 32];
  const int tid = threadIdx.x;
  const int w = tid >> 6, lane = tid & 63;
  const int m0 = blockIdx.y * 128, n0 = blockIdx.x * 128;
  const u16* Atile = A + (size_t)m0 * K;
  const u16* Btile = Bt + (size_t)n0 * K;
  const int r = tid >> 2, c = (tid & 3) * 8;
  const int wm = (w >> 1) * 64, wn = (w & 1) * 64;

  f32x4 acc[4][4] = {};
  const int NT = K / 32;

  {  // stage tile 0
    const u16* ga = Atile + (size_t)r * K + c;
    const u16* gb = Btile + (size_t)r * K + c;
    u16* lb = lds[0];
    gload16(ga, lb + w * 512);
    gload16(ga + (size_t)64 * K, lb + 2048 + w * 512);
    gload16(gb, lb + 4096 + w * 512);
    gload16(gb + (size_t)64 * K, lb + 4096 + 2048 + w * 512);
  }
  int cur = 0;
  for (int t = 0; t < NT; ++t) {
    __syncthreads();
    if (t + 1 < NT) {
      const u16* ga = Atile + (size_t)r * K + (t + 1) * 32 + c;
      const u16* gb = Btile + (size_t)r * K + (t + 1) * 32 + c;
      u16* lb = lds[cur ^ 1];
      gload16(ga, lb + w * 512);
      gload16(ga + (size_t)64 * K, lb + 2048 + w * 512);
      gload16(gb, lb + 4096 + w * 512);
      gload16(gb + (size_t)64 * K, lb + 4096 + 2048 + w * 512);
    }
    const u16* lA = lds[cur];
    const u16* lB = lds[cur] + 4096;
    bf16x8 af[4], bfv[4];
#pragma unroll
    for (int mi = 0; mi < 4; ++mi)
      af[mi] = *reinterpret_cast<const bf16x8*>(
          lA + (wm + mi * 16 + (lane & 15)) * 32 + (lane >> 4) * 8);
#pragma unroll
    for (int ni = 0; ni < 4; ++ni)
      bfv[ni] = *reinterpret_cast<const bf16x8*>(
          lB + (wn + ni * 16 + (lane & 15)) * 32 + (lane >> 4) * 8);
#pragma unroll
    for (int mi = 0; mi < 4; ++mi)
#pragma unroll
      for (int ni = 0; ni < 4; ++ni)
        acc[mi][ni] = __builtin_amdgcn_mfma_f32_16x16x32_bf16(af[mi], bfv[ni],
                                                              acc[mi][ni], 0, 0, 0);
    cur ^= 1;
  }
  // epilogue
#pragma unroll
  for (int mi = 0; mi < 4; ++mi) {
#pragma unroll
    for (int ni = 0; ni < 4; ++ni) {
      int colg = n0 + wn + ni * 16 + (lane & 15);
      float bv = bias[colg];
#pragma unroll
      for (int rr = 0; rr < 4; ++rr) {
        int rowg = m0 + wm + mi * 16 + ((lane >> 4) << 2) + rr;
        float v = acc[mi][ni][rr] + bv;
        if (MODE == 1) {
          Cf[(size_t)rowg * N + colg] = v;
        } else {
          if (colg < D_MODEL) {
            // Q: fold softmax scale*log2e here (saves a mul/score in flash)
            u16 b = f2bf(v * 0.1803368801111f);
            int hh = colg >> 6, dd = colg & 63;
            Qd[((size_t)hh * S_LEN + rowg) * 64 + swz(rowg, dd)] = b;
          } else if (colg < 2 * D_MODEL) {
            u16 b = f2bf(v);
            int cc = colg - D_MODEL;
            int hh = cc >> 6, dd = cc & 63;
            Kd[((size_t)hh * S_LEN + rowg) * 64 + swz(rowg, dd)] = b;
          } else {
            u16 b = f2bf(v);
            int cc = colg - 2 * D_MODEL;
            int hh = cc >> 6, dd = cc & 63;
            int sl = rowg & 63;
            Vtd[((size_t)hh * 64 + dd) * S_LEN + (rowg & ~63) + swz(dd, sl)] = b;
          }
        }
      }
    }
  }
}

// ---------------- flash attention (causal), 64-row Q tiles ----------------
// 1D grid 1024: qt = 63 - (bid>>4), h = bid&15 -> GLOBAL longest-first dispatch.
// Q direct global->reg (pre-scaled, pre-swizzled); LDS 40KB -> 4 blocks/CU.
// K/V double-buffered, issue-early staging. Softmax VALU-thinned:
//  - scores arrive already in exp2 domain (Q pre-scaled)
//  - per-lane partial l, single shfl-reduce at epilogue (T13-adjacent)
//  - defer-max (THR=8): skip alpha/oacc rescale while max grows <= 8
__global__ __launch_bounds__(256) void k_flash(const u16* __restrict__ Qd,
                                               const u16* __restrict__ Kd,
                                               const u16* __restrict__ Vtd,
                                               u16* __restrict__ Ao) {
  __shared__ __align__(16) u16 Ks[2][64 * 64];
  __shared__ __align__(16) u16 Vs[2][64 * 64];
  __shared__ __align__(16) u16 Ps[4][16 * 64];
  const int tid = threadIdx.x, w = tid >> 6, lane = tid & 63;
  const int bid = blockIdx.x;
  const int qt = 63 - (bid >> 4), h = bid & 15;
  const u16* Qh = Qd + (size_t)h * S_LEN * 64;
  const u16* Kh = Kd + (size_t)h * S_LEN * 64;
  const u16* Vh = Vtd + (size_t)h * 64 * S_LEN;
  const int r8 = tid >> 3, c8 = (tid & 7) * 8;

  {  // prologue: stage K/V tile 0
    const u16* gk = Kh + (size_t)r8 * 64 + c8;
    gload16(gk, Ks[0] + w * 512);
    gload16(gk + 32 * 64, Ks[0] + 2048 + w * 512);
    const u16* gv = Vh + (size_t)r8 * S_LEN + c8;
    gload16(gv, Vs[0] + w * 512);
    gload16(gv + (size_t)32 * S_LEN, Vs[0] + 2048 + w * 512);
  }

  // Q fragments: direct global->reg (layout already swizzled + scaled)
  bf16x8 qa[2];
  {
    const int rq = qt * 64 + w * 16 + (lane & 15);
#pragma unroll
    for (int kk = 0; kk < 2; ++kk)
      qa[kk] = *reinterpret_cast<const bf16x8*>(
          Qh + (size_t)rq * 64 + swz(rq, kk * 32 + (lane >> 4) * 8));
  }

  float m_run[4], l_part[4];  // l_part: per-LANE partial sum (reduced at end)
  f32x4 oacc[4] = {};
#pragma unroll
  for (int rr = 0; rr < 4; ++rr) {
    m_run[rr] = -1e30f;
    l_part[rr] = 0.f;
  }

  __syncthreads();  // K/V tile 0 landed

  int cur = 0;
  for (int j = 0; j <= qt; ++j) {
    // issue next tile's staging BEFORE compute (latency hides under compute)
    if (j < qt) {
      const u16* gk = Kh + ((size_t)((j + 1) * 64 + r8)) * 64 + c8;
      gload16(gk, Ks[cur ^ 1] + w * 512);
      gload16(gk + 32 * 64, Ks[cur ^ 1] + 2048 + w * 512);
      const u16* gv = Vh + (size_t)r8 * S_LEN + (j + 1) * 64 + c8;
      gload16(gv, Vs[cur ^ 1] + w * 512);
      gload16(gv + (size_t)32 * S_LEN, Vs[cur ^ 1] + 2048 + w * 512);
    }

    // S = Q K^T   (wave w owns Q rows [w*16, w*16+16)); scores in exp2 domain
    f32x4 sacc[4] = {};
#pragma unroll
    for (int kk = 0; kk < 2; ++kk) {
#pragma unroll
      for (int ni = 0; ni < 4; ++ni) {
        const int kvl = ni * 16 + (lane & 15);
        bf16x8 kb = *reinterpret_cast<const bf16x8*>(
            Ks[cur] + kvl * 64 + swz(kvl, kk * 32 + (lane >> 4) * 8));
        sacc[ni] = __builtin_amdgcn_mfma_f32_16x16x32_bf16(qa[kk], kb, sacc[ni], 0, 0, 0);
      }
    }

    float pvv[4][4];
#pragma unroll
    for (int ni = 0; ni < 4; ++ni)
#pragma unroll
      for (int rr = 0; rr < 4; ++rr) pvv[ni][rr] = sacc[ni][rr];

    if (j == qt) {  // diagonal tile: causal mask (wave-uniform branch)
      const int rowb = qt * 64 + w * 16 + ((lane >> 4) << 2);
#pragma unroll
      for (int ni = 0; ni < 4; ++ni) {
        const int col = j * 64 + ni * 16 + (lane & 15);
#pragma unroll
        for (int rr = 0; rr < 4; ++rr)
          if (col > rowb + rr) pvv[ni][rr] = -1e30f;
      }
    }

    // row max (local + 16-lane shfl tree)
    float mx[4];
#pragma unroll
    for (int rr = 0; rr < 4; ++rr) {
      float m_ = fmaxf(fmaxf(pvv[0][rr], pvv[1][rr]), fmaxf(pvv[2][rr], pvv[3][rr]));
#pragma unroll
      for (int d = 1; d < 16; d <<= 1) m_ = fmaxf(m_, __shfl_xor(m_, d));
      mx[rr] = m_;
    }

    // defer-max: rescale only if some row's max grew by > 8 (wave-uniform)
    bool need = (mx[0] > m_run[0] + 8.f) | (mx[1] > m_run[1] + 8.f) |
                (mx[2] > m_run[2] + 8.f) | (mx[3] > m_run[3] + 8.f);
    if (__any(need)) {
#pragma unroll
      for (int rr = 0; rr < 4; ++rr) {
        float mn = fmaxf(m_run[rr], mx[rr]);
        float alpha = exp2f(m_run[rr] - mn);
        m_run[rr] = mn;
        l_part[rr] *= alpha;
#pragma unroll
        for (int ni = 0; ni < 4; ++ni) oacc[ni][rr] *= alpha;
      }
    }

    // P = exp2(S - m_run); accumulate per-lane partial l (no shfl here)
#pragma unroll
    for (int rr = 0; rr < 4; ++rr) {
      float rs = 0.f;
#pragma unroll
      for (int ni = 0; ni < 4; ++ni) {
        float p = exp2f(pvv[ni][rr] - m_run[rr]);
        pvv[ni][rr] = p;
        rs += p;
      }
      l_part[rr] += rs;
    }

    // P -> LDS (per-wave private buffer; same-wave write->read, no barrier)
#pragma unroll
    for (int ni = 0; ni < 4; ++ni)
#pragma unroll
      for (int rr = 0; rr < 4; ++rr) {
        int rowl = ((lane >> 4) << 2) + rr;
        int coll = ni * 16 + (lane & 15);
        Ps[w][rowl * 64 + swz(rowl, coll)] = f2bf(pvv[ni][rr]);
      }

    // O += P V
#pragma unroll
    for (int kk = 0; kk < 2; ++kk) {
      const int pr = lane & 15;
      bf16x8 pa = *reinterpret_cast<const bf16x8*>(
          Ps[w] + pr * 64 + swz(pr, kk * 32 + (lane >> 4) * 8));
#pragma unroll
      for (int ni = 0; ni < 4; ++ni) {
        const int dd = ni * 16 + (lane & 15);
        bf16x8 vb = *reinterpret_cast<const bf16x8*>(
            Vs[cur] + dd * 64 + swz(dd, kk * 32 + (lane >> 4) * 8));
        oacc[ni] = __builtin_amdgcn_mfma_f32_16x16x32_bf16(pa, vb, oacc[ni], 0, 0, 0);
      }
    }

    __syncthreads();  // drains vmcnt (next tile landed) + all waves done with cur
    cur ^= 1;
  }

  // epilogue: reduce per-lane l partials over the 16-lane row group, write O
#pragma unroll
  for (int rr = 0; rr < 4; ++rr) {
    float l = l_part[rr];
#pragma unroll
    for (int d = 1; d < 16; d <<= 1) l += __shfl_xor(l, d);
    float inv = 1.f / l;
    int rowg = qt * 64 + w * 16 + ((lane >> 4) << 2) + rr;
#pragma unroll
    for (int ni = 0; ni < 4; ++ni) {
      int colg = h * 64 + ni * 16 + (lane & 15);
      Ao[(size_t)rowg * D_MODEL + colg] = f2bf(oacc[ni][rr] * inv);
    }
  }
}

extern "C" void kernel_launch(void* const* d_in, const int* in_sizes, int n_in,
                              void* d_out, int out_size, void* d_ws, size_t ws_size,
                              hipStream_t stream) {
  const float* x = (const float*)d_in[0];
  const float* Wqkv = (const float*)d_in[1];
  const float* bqkv = (const float*)d_in[2];
  const float* Wproj = (const float*)d_in[3];
  const float* bproj = (const float*)d_in[4];
  float* out = (float*)d_out;
  char* ws = (char*)d_ws;

  // Workspace map (40 MB total; aout aliases xb, which is dead after k_gemm<0>):
  u16* xb = (u16*)(ws);                            // [0,8) MB   x as bf16
  u16* aout = (u16*)(ws);                          // [0,8) MB   attn out (reuses xb)
  u16* wqkvt = (u16*)(ws + (size_t)(8 << 20));     // [8,14) MB  Wqkv^T bf16
  u16* wprojt = (u16*)(ws + (size_t)(14 << 20));   // [14,16) MB Wproj^T bf16
  u16* Qd = (u16*)(ws + (size_t)(16 << 20));       // [16,24) MB
  u16* Kd = (u16*)(ws + (size_t)(24 << 20));       // [24,32) MB
  u16* Vtd = (u16*)(ws + (size_t)(32 << 20));      // [32,40) MB

  if (ws_size < (size_t)(40 << 20)) return;  // refuse to scribble OOB

  k_conv<<<dim3(4096), dim3(256), 0, stream>>>(x, xb, S_LEN * D_MODEL);
  k_transpose_conv<<<dim3(96, 32), dim3(32, 8), 0, stream>>>(Wqkv, wqkvt, D_MODEL,
                                                             3 * D_MODEL);
  k_transpose_conv<<<dim3(32, 32), dim3(32, 8), 0, stream>>>(Wproj, wprojt, D_MODEL,
                                                             D_MODEL);
  k_gemm<0><<<dim3(24, 32), dim3(256), 0, stream>>>(xb, wqkvt, bqkv, nullptr, Qd, Kd,
                                                    Vtd, S_LEN, 3 * D_MODEL, D_MODEL);
  k_flash<<<dim3(1024), dim3(256), 0, stream>>>(Qd, Kd, Vtd, aout);
  k_gemm<1><<<dim3(8, 32), dim3(256), 0, stream>>>(aout, wprojt, bproj, out, nullptr,
                                                   nullptr, nullptr, S_LEN, D_MODEL,
                                                   D_MODEL);
}

// Round 13
// 226.947 us; speedup vs baseline: 1.5640x; 1.1145x over previous
//
#include <hip/hip_runtime.h>
#include <stdint.h>

typedef unsigned short u16;
typedef unsigned u32;
typedef __bf16 bf16x8 __attribute__((ext_vector_type(8)));
typedef float f32x4 __attribute__((ext_vector_type(4)));
typedef u32 u32x4 __attribute__((ext_vector_type(4)));

#define S_LEN 4096
#define D_MODEL 1024
#define NHEAD 16
#define HDIM 64

__device__ __forceinline__ u16 f2bf(float f) {
  unsigned u = __builtin_bit_cast(unsigned, f);
  u += 0x7fffu + ((u >> 16) & 1u);
  return (u16)(u >> 16);
}

__device__ __forceinline__ u32 cvt_pk_bf16(float lo, float hi) {
  u32 r;
  asm("v_cvt_pk_bf16_f32 %0, %1, %2" : "=v"(r) : "v"(lo), "v"(hi));
  return r;
}

// XOR swizzle of 16B units within a 128B (64 x bf16) row: unit ^= row&7
__device__ __forceinline__ int swz(int row, int col) {
  return (((col >> 3) ^ (row & 7)) << 3) | (col & 7);
}

// sigma: kv-slot permutation within a 64-row V tile so that flash's PV
// A-fragment (P packed LOCALLY per lane, slots j=0..7 <-> kv=16*(2kk2+(j>>2))+4g+(j&3))
// matches a plain b128 read of V. c = sigma(s):
__device__ __forceinline__ int sigma64(int s) {
  int a = s >> 4;
  return ((a >> 1) << 5) | (((s >> 2) & 3) << 3) | ((a & 1) << 2) | (s & 3);
}

__device__ __forceinline__ void gload16(const void* g, void* l) {
  auto gp = reinterpret_cast<__attribute__((address_space(1))) void*>(
      reinterpret_cast<uintptr_t>(g));
  auto lp = reinterpret_cast<__attribute__((address_space(3))) void*>(
      static_cast<unsigned>(reinterpret_cast<uintptr_t>(l)));
  __builtin_amdgcn_global_load_lds(gp, lp, 16, 0, 0);
}

// ---------------- fp32 -> bf16 elementwise ----------------
__global__ __launch_bounds__(256) void k_conv(const float* __restrict__ in,
                                              u16* __restrict__ out, int n) {
  int i = (blockIdx.x * 256 + threadIdx.x) * 4;
  if (i >= n) return;
  float4 v = *reinterpret_cast<const float4*>(in + i);
  ushort4 o = make_ushort4(f2bf(v.x), f2bf(v.y), f2bf(v.z), f2bf(v.w));
  *reinterpret_cast<ushort4*>(out + i) = o;
}

// ---------------- fp32 [R][C] -> bf16 [C][R] ----------------
__global__ __launch_bounds__(256) void k_transpose_conv(const float* __restrict__ in,
                                                        u16* __restrict__ out,
                                                        int R, int C) {
  __shared__ float tile[32][33];
  int c0 = blockIdx.x * 32, r0 = blockIdx.y * 32;
  int tx = threadIdx.x, ty = threadIdx.y;
#pragma unroll
  for (int j = 0; j < 4; ++j)
    tile[ty + j * 8][tx] = in[(size_t)(r0 + ty + j * 8) * C + c0 + tx];
  __syncthreads();
#pragma unroll
  for (int j = 0; j < 4; ++j)
    out[(size_t)(c0 + ty + j * 8) * R + r0 + tx] = f2bf(tile[tx][ty + j * 8]);
}

// ---------------- bf16 GEMM: C[M,N] = A[M,K] * Bt[N,K]^T + bias ----------------
// MODE 0: scatter into Q/K/Vt per-head bf16 layouts (XOR swizzle; Q pre-scaled
//         by 0.125*log2e; V columns sigma-permuted for flash's local P-pack PV)
// MODE 1: fp32 output, row-major
template <int MODE>
__global__ __launch_bounds__(256) void k_gemm(
    const u16* __restrict__ A, const u16* __restrict__ Bt,
    const float* __restrict__ bias, float* __restrict__ Cf,
    u16* __restrict__ Qd, u16* __restrict__ Kd, u16* __restrict__ Vtd,
    int M, int N, int K) {
  __shared__ __align__(16) u16 lds[2][2 * 128 * 32];
  const int tid = threadIdx.x;
  const int w = tid >> 6, lane = tid & 63;
  const int m0 = blockIdx.y * 128, n0 = blockIdx.x * 128;
  const u16* Atile = A + (size_t)m0 * K;
  const u16* Btile = Bt + (size_t)n0 * K;
  const int r = tid >> 2, c = (tid & 3) * 8;
  const int wm = (w >> 1) * 64, wn = (w & 1) * 64;

  f32x4 acc[4][4] = {};
  const int NT = K / 32;

  {  // stage tile 0
    const u16* ga = Atile + (size_t)r * K + c;
    const u16* gb = Btile + (size_t)r * K + c;
    u16* lb = lds[0];
    gload16(ga, lb + w * 512);
    gload16(ga + (size_t)64 * K, lb + 2048 + w * 512);
    gload16(gb, lb + 4096 + w * 512);
    gload16(gb + (size_t)64 * K, lb + 4096 + 2048 + w * 512);
  }
  int cur = 0;
  for (int t = 0; t < NT; ++t) {
    __syncthreads();
    if (t + 1 < NT) {
      const u16* ga = Atile + (size_t)r * K + (t + 1) * 32 + c;
      const u16* gb = Btile + (size_t)r * K + (t + 1) * 32 + c;
      u16* lb = lds[cur ^ 1];
      gload16(ga, lb + w * 512);
      gload16(ga + (size_t)64 * K, lb + 2048 + w * 512);
      gload16(gb, lb + 4096 + w * 512);
      gload16(gb + (size_t)64 * K, lb + 4096 + 2048 + w * 512);
    }
    const u16* lA = lds[cur];
    const u16* lB = lds[cur] + 4096;
    bf16x8 af[4], bfv[4];
#pragma unroll
    for (int mi = 0; mi < 4; ++mi)
      af[mi] = *reinterpret_cast<const bf16x8*>(
          lA + (wm + mi * 16 + (lane & 15)) * 32 + (lane >> 4) * 8);
#pragma unroll
    for (int ni = 0; ni < 4; ++ni)
      bfv[ni] = *reinterpret_cast<const bf16x8*>(
          lB + (wn + ni * 16 + (lane & 15)) * 32 + (lane >> 4) * 8);
#pragma unroll
    for (int mi = 0; mi < 4; ++mi)
#pragma unroll
      for (int ni = 0; ni < 4; ++ni)
        acc[mi][ni] = __builtin_amdgcn_mfma_f32_16x16x32_bf16(af[mi], bfv[ni],
                                                              acc[mi][ni], 0, 0, 0);
    cur ^= 1;
  }
  // epilogue
#pragma unroll
  for (int mi = 0; mi < 4; ++mi) {
#pragma unroll
    for (int ni = 0; ni < 4; ++ni) {
      int colg = n0 + wn + ni * 16 + (lane & 15);
      float bv = bias[colg];
#pragma unroll
      for (int rr = 0; rr < 4; ++rr) {
        int rowg = m0 + wm + mi * 16 + ((lane >> 4) << 2) + rr;
        float v = acc[mi][ni][rr] + bv;
        if (MODE == 1) {
          Cf[(size_t)rowg * N + colg] = v;
        } else {
          if (colg < D_MODEL) {
            // Q: fold softmax scale*log2e here (saves a mul/score in flash)
            u16 b = f2bf(v * 0.1803368801111f);
            int hh = colg >> 6, dd = colg & 63;
            Qd[((size_t)hh * S_LEN + rowg) * 64 + swz(rowg, dd)] = b;
          } else if (colg < 2 * D_MODEL) {
            u16 b = f2bf(v);
            int cc = colg - D_MODEL;
            int hh = cc >> 6, dd = cc & 63;
            Kd[((size_t)hh * S_LEN + rowg) * 64 + swz(rowg, dd)] = b;
          } else {
            u16 b = f2bf(v);
            int cc = colg - 2 * D_MODEL;
            int hh = cc >> 6, dd = cc & 63;
            int csl = sigma64(rowg & 63);  // sigma-permute kv within 64-tile
            Vtd[((size_t)hh * 64 + dd) * S_LEN + (rowg & ~63) + swz(dd, csl)] = b;
          }
        }
      }
    }
  }
}

// ---------------- flash attention (causal), 64-row Q tiles ----------------
// 1D grid 1024, global LPT dispatch. Swapped QK^T: S^T = mfma(K,Q) -> each lane
// owns ONE q-row's P (q=lane&15, kv=16ni+4g+rr). Softmax fully per-lane
// (2 shfl_xor for row max). P packed LOCALLY via v_cvt_pk_bf16_f32 into PV's
// A-fragment; V's sigma-permuted layout makes vb a plain b128 read. No P LDS
// buffer -> 32KB LDS. Defer-max THR=8; alpha/inv moved to oacc rows (q=4g+rr)
// with 4 shfls at rescale events / epilogue only.
__global__ __launch_bounds__(256) void k_flash(const u16* __restrict__ Qd,
                                               const u16* __restrict__ Kd,
                                               const u16* __restrict__ Vtd,
                                               u16* __restrict__ Ao) {
  __shared__ __align__(16) u16 Ks[2][64 * 64];
  __shared__ __align__(16) u16 Vs[2][64 * 64];
  const int tid = threadIdx.x, w = tid >> 6, lane = tid & 63;
  const int bid = blockIdx.x;
  const int qt = 63 - (bid >> 4), h = bid & 15;
  const u16* Qh = Qd + (size_t)h * S_LEN * 64;
  const u16* Kh = Kd + (size_t)h * S_LEN * 64;
  const u16* Vh = Vtd + (size_t)h * 64 * S_LEN;
  const int r8 = tid >> 3, c8 = (tid & 7) * 8;
  const int g = lane >> 4, ql = lane & 15;

  {  // prologue: stage K/V tile 0
    const u16* gk = Kh + (size_t)r8 * 64 + c8;
    gload16(gk, Ks[0] + w * 512);
    gload16(gk + 32 * 64, Ks[0] + 2048 + w * 512);
    const u16* gv = Vh + (size_t)r8 * S_LEN + c8;
    gload16(gv, Vs[0] + w * 512);
    gload16(gv + (size_t)32 * S_LEN, Vs[0] + 2048 + w * 512);
  }

  // Q fragments: direct global->reg (layout already swizzled + scaled)
  bf16x8 qa[2];
  {
    const int rq = qt * 64 + w * 16 + ql;
#pragma unroll
    for (int kk = 0; kk < 2; ++kk)
      qa[kk] = *reinterpret_cast<const bf16x8*>(
          Qh + (size_t)rq * 64 + swz(rq, kk * 32 + g * 8));
  }

  float m_run = -1e30f, l_part = 0.f;  // per-lane: q-row = w*16+ql
  f32x4 oacc[4] = {};                  // O[q=4g+rr][d=16ni+ql]

  __syncthreads();  // K/V tile 0 landed

  int cur = 0;
  for (int j = 0; j <= qt; ++j) {
    // issue next tile's staging BEFORE compute (latency hides under compute)
    if (j < qt) {
      const u16* gk = Kh + ((size_t)((j + 1) * 64 + r8)) * 64 + c8;
      gload16(gk, Ks[cur ^ 1] + w * 512);
      gload16(gk + 32 * 64, Ks[cur ^ 1] + 2048 + w * 512);
      const u16* gv = Vh + (size_t)r8 * S_LEN + (j + 1) * 64 + c8;
      gload16(gv, Vs[cur ^ 1] + w * 512);
      gload16(gv + (size_t)32 * S_LEN, Vs[cur ^ 1] + 2048 + w * 512);
    }

    // S^T = K Q^T : lane holds P[q=w*16+ql][kv=16ni+4g+rr] (exp2 domain)
    f32x4 sacc[4] = {};
#pragma unroll
    for (int kk = 0; kk < 2; ++kk) {
#pragma unroll
      for (int ni = 0; ni < 4; ++ni) {
        const int kvl = ni * 16 + ql;
        bf16x8 kb = *reinterpret_cast<const bf16x8*>(
            Ks[cur] + kvl * 64 + swz(kvl, kk * 32 + g * 8));
        sacc[ni] = __builtin_amdgcn_mfma_f32_16x16x32_bf16(kb, qa[kk], sacc[ni], 0, 0, 0);
      }
    }

    float pvv[4][4];
#pragma unroll
    for (int ni = 0; ni < 4; ++ni)
#pragma unroll
      for (int rr = 0; rr < 4; ++rr) pvv[ni][rr] = sacc[ni][rr];

    if (j == qt) {  // diagonal tile: causal mask (wave-uniform branch)
      const int qoff = w * 16 + ql;
#pragma unroll
      for (int ni = 0; ni < 4; ++ni)
#pragma unroll
        for (int rr = 0; rr < 4; ++rr)
          if (ni * 16 + g * 4 + rr > qoff) pvv[ni][rr] = -1e30f;
    }

    // row max: local over lane's 16 kv + 2-step cross-group combine
    float mx;
    {
      float a0 = fmaxf(fmaxf(pvv[0][0], pvv[0][1]), fmaxf(pvv[0][2], pvv[0][3]));
      float a1 = fmaxf(fmaxf(pvv[1][0], pvv[1][1]), fmaxf(pvv[1][2], pvv[1][3]));
      float a2 = fmaxf(fmaxf(pvv[2][0], pvv[2][1]), fmaxf(pvv[2][2], pvv[2][3]));
      float a3 = fmaxf(fmaxf(pvv[3][0], pvv[3][1]), fmaxf(pvv[3][2], pvv[3][3]));
      mx = fmaxf(fmaxf(a0, a1), fmaxf(a2, a3));
      mx = fmaxf(mx, __shfl_xor(mx, 16));
      mx = fmaxf(mx, __shfl_xor(mx, 32));
    }

    // defer-max: rescale only if some row's max grew by > 8 (wave-uniform)
    if (__any(mx > m_run + 8.f)) {
      float mn = fmaxf(m_run, mx);
      float alpha = exp2f(m_run - mn);
      m_run = mn;
      l_part *= alpha;
      float ao[4];
#pragma unroll
      for (int rr = 0; rr < 4; ++rr) ao[rr] = __shfl(alpha, g * 4 + rr);
#pragma unroll
      for (int ni = 0; ni < 4; ++ni)
#pragma unroll
        for (int rr = 0; rr < 4; ++rr) oacc[ni][rr] *= ao[rr];
    }

    // P = exp2(S - m); per-lane partial l; pack to bf16 A-fragments locally
    u32 pk[4][2];
    {
      float rs = 0.f;
#pragma unroll
      for (int ni = 0; ni < 4; ++ni) {
        float p0 = exp2f(pvv[ni][0] - m_run);
        float p1 = exp2f(pvv[ni][1] - m_run);
        float p2 = exp2f(pvv[ni][2] - m_run);
        float p3 = exp2f(pvv[ni][3] - m_run);
        rs += (p0 + p1) + (p2 + p3);
        pk[ni][0] = cvt_pk_bf16(p0, p1);
        pk[ni][1] = cvt_pk_bf16(p2, p3);
      }
      l_part += rs;
    }

    // O += P V  (pa local; vb plain b128 thanks to sigma-permuted V layout)
#pragma unroll
    for (int kk2 = 0; kk2 < 2; ++kk2) {
      u32x4 pw = {pk[2 * kk2][0], pk[2 * kk2][1], pk[2 * kk2 + 1][0], pk[2 * kk2 + 1][1]};
      bf16x8 pa = __builtin_bit_cast(bf16x8, pw);
#pragma unroll
      for (int ni = 0; ni < 4; ++ni) {
        const int dd = ni * 16 + ql;
        bf16x8 vb = *reinterpret_cast<const bf16x8*>(
            Vs[cur] + dd * 64 + swz(dd, kk2 * 32 + g * 8));
        oacc[ni] = __builtin_amdgcn_mfma_f32_16x16x32_bf16(pa, vb, oacc[ni], 0, 0, 0);
      }
    }

    __syncthreads();  // drains vmcnt (next tile landed) + all waves done with cur
    cur ^= 1;
  }

  // epilogue: reduce l across the 4 kv-groups, redistribute to oacc rows, write O
  {
    float l = l_part;
    l += __shfl_xor(l, 16);
    l += __shfl_xor(l, 32);
    float inv = 1.f / l;
    float io[4];
#pragma unroll
    for (int rr = 0; rr < 4; ++rr) io[rr] = __shfl(inv, g * 4 + rr);
#pragma unroll
    for (int rr = 0; rr < 4; ++rr) {
      int rowg = qt * 64 + w * 16 + g * 4 + rr;
#pragma unroll
      for (int ni = 0; ni < 4; ++ni) {
        int colg = h * 64 + ni * 16 + ql;
        Ao[(size_t)rowg * D_MODEL + colg] = f2bf(oacc[ni][rr] * io[rr]);
      }
    }
  }
}

extern "C" void kernel_launch(void* const* d_in, const int* in_sizes, int n_in,
                              void* d_out, int out_size, void* d_ws, size_t ws_size,
                              hipStream_t stream) {
  const float* x = (const float*)d_in[0];
  const float* Wqkv = (const float*)d_in[1];
  const float* bqkv = (const float*)d_in[2];
  const float* Wproj = (const float*)d_in[3];
  const float* bproj = (const float*)d_in[4];
  float* out = (float*)d_out;
  char* ws = (char*)d_ws;

  // Workspace map (40 MB total; aout aliases xb, which is dead after k_gemm<0>):
  u16* xb = (u16*)(ws);                            // [0,8) MB   x as bf16
  u16* aout = (u16*)(ws);                          // [0,8) MB   attn out (reuses xb)
  u16* wqkvt = (u16*)(ws + (size_t)(8 << 20));     // [8,14) MB  Wqkv^T bf16
  u16* wprojt = (u16*)(ws + (size_t)(14 << 20));   // [14,16) MB Wproj^T bf16
  u16* Qd = (u16*)(ws + (size_t)(16 << 20));       // [16,24) MB
  u16* Kd = (u16*)(ws + (size_t)(24 << 20));       // [24,32) MB
  u16* Vtd = (u16*)(ws + (size_t)(32 << 20));      // [32,40) MB

  if (ws_size < (size_t)(40 << 20)) return;  // refuse to scribble OOB

  k_conv<<<dim3(4096), dim3(256), 0, stream>>>(x, xb, S_LEN * D_MODEL);
  k_transpose_conv<<<dim3(96, 32), dim3(32, 8), 0, stream>>>(Wqkv, wqkvt, D_MODEL,
                                                             3 * D_MODEL);
  k_transpose_conv<<<dim3(32, 32), dim3(32, 8), 0, stream>>>(Wproj, wprojt, D_MODEL,
                                                             D_MODEL);
  k_gemm<0><<<dim3(24, 32), dim3(256), 0, stream>>>(xb, wqkvt, bqkv, nullptr, Qd, Kd,
                                                    Vtd, S_LEN, 3 * D_MODEL, D_MODEL);
  k_flash<<<dim3(1024), dim3(256), 0, stream>>>(Qd, Kd, Vtd, aout);
  k_gemm<1><<<dim3(8, 32), dim3(256), 0, stream>>>(aout, wprojt, bproj, out, nullptr,
                                                   nullptr, nullptr, S_LEN, D_MODEL,
                                                   D_MODEL);
}

// Round 14
// 224.288 us; speedup vs baseline: 1.5826x; 1.0119x over previous
//
#include <hip/hip_runtime.h>
#include <stdint.h>

typedef unsigned short u16;
typedef unsigned u32;
typedef __bf16 bf16x8 __attribute__((ext_vector_type(8)));
typedef float f32x4 __attribute__((ext_vector_type(4)));
typedef u32 u32x4 __attribute__((ext_vector_type(4)));

#define S_LEN 4096
#define D_MODEL 1024
#define NHEAD 16
#define HDIM 64

__device__ __forceinline__ u16 f2bf(float f) {
  unsigned u = __builtin_bit_cast(unsigned, f);
  u += 0x7fffu + ((u >> 16) & 1u);
  return (u16)(u >> 16);
}

__device__ __forceinline__ u32 cvt_pk_bf16(float lo, float hi) {
  u32 r;
  asm("v_cvt_pk_bf16_f32 %0, %1, %2" : "=v"(r) : "v"(lo), "v"(hi));
  return r;
}

// XOR swizzle of 16B units within a 128B (64 x bf16) row: unit ^= row&7
__device__ __forceinline__ int swz(int row, int col) {
  return (((col >> 3) ^ (row & 7)) << 3) | (col & 7);
}

// sigma: kv-slot permutation within a 64-row V tile so that flash's PV
// A-fragment (P packed LOCALLY per lane, slots j=0..7 <-> kv=16*(2kk2+(j>>2))+4g+(j&3))
// matches a plain b128 read of V. c = sigma(s):
__device__ __forceinline__ int sigma64(int s) {
  int a = s >> 4;
  return ((a >> 1) << 5) | (((s >> 2) & 3) << 3) | ((a & 1) << 2) | (s & 3);
}

__device__ __forceinline__ void gload16(const void* g, void* l) {
  auto gp = reinterpret_cast<__attribute__((address_space(1))) void*>(
      reinterpret_cast<uintptr_t>(g));
  auto lp = reinterpret_cast<__attribute__((address_space(3))) void*>(
      static_cast<unsigned>(reinterpret_cast<uintptr_t>(l)));
  __builtin_amdgcn_global_load_lds(gp, lp, 16, 0, 0);
}

// ---------------- fp32 -> bf16 elementwise ----------------
__global__ __launch_bounds__(256) void k_conv(const float* __restrict__ in,
                                              u16* __restrict__ out, int n) {
  int i = (blockIdx.x * 256 + threadIdx.x) * 4;
  if (i >= n) return;
  float4 v = *reinterpret_cast<const float4*>(in + i);
  ushort4 o = make_ushort4(f2bf(v.x), f2bf(v.y), f2bf(v.z), f2bf(v.w));
  *reinterpret_cast<ushort4*>(out + i) = o;
}

// ---------------- fp32 [R][C] -> bf16 [C][R] ----------------
__global__ __launch_bounds__(256) void k_transpose_conv(const float* __restrict__ in,
                                                        u16* __restrict__ out,
                                                        int R, int C) {
  __shared__ float tile[32][33];
  int c0 = blockIdx.x * 32, r0 = blockIdx.y * 32;
  int tx = threadIdx.x, ty = threadIdx.y;
#pragma unroll
  for (int j = 0; j < 4; ++j)
    tile[ty + j * 8][tx] = in[(size_t)(r0 + ty + j * 8) * C + c0 + tx];
  __syncthreads();
#pragma unroll
  for (int j = 0; j < 4; ++j)
    out[(size_t)(c0 + ty + j * 8) * R + r0 + tx] = f2bf(tile[tx][ty + j * 8]);
}

// ---------------- bf16 GEMM: C[M,N] = A[M,K] * Bt[N,K]^T + bias ----------------
// MODE 0: scatter into Q/K/Vt per-head bf16 layouts (XOR swizzle; Q pre-scaled
//         by 0.125*log2e; V columns sigma-permuted for flash's local P-pack PV)
// MODE 1: fp32 output, row-major
template <int MODE>
__global__ __launch_bounds__(256) void k_gemm(
    const u16* __restrict__ A, const u16* __restrict__ Bt,
    const float* __restrict__ bias, float* __restrict__ Cf,
    u16* __restrict__ Qd, u16* __restrict__ Kd, u16* __restrict__ Vtd,
    int M, int N, int K) {
  __shared__ __align__(16) u16 lds[2][2 * 128 * 32];
  const int tid = threadIdx.x;
  const int w = tid >> 6, lane = tid & 63;
  const int m0 = blockIdx.y * 128, n0 = blockIdx.x * 128;
  const u16* Atile = A + (size_t)m0 * K;
  const u16* Btile = Bt + (size_t)n0 * K;
  const int r = tid >> 2, c = (tid & 3) * 8;
  const int wm = (w >> 1) * 64, wn = (w & 1) * 64;

  f32x4 acc[4][4] = {};
  const int NT = K / 32;

  {  // stage tile 0
    const u16* ga = Atile + (size_t)r * K + c;
    const u16* gb = Btile + (size_t)r * K + c;
    u16* lb = lds[0];
    gload16(ga, lb + w * 512);
    gload16(ga + (size_t)64 * K, lb + 2048 + w * 512);
    gload16(gb, lb + 4096 + w * 512);
    gload16(gb + (size_t)64 * K, lb + 4096 + 2048 + w * 512);
  }
  int cur = 0;
  for (int t = 0; t < NT; ++t) {
    __syncthreads();
    if (t + 1 < NT) {
      const u16* ga = Atile + (size_t)r * K + (t + 1) * 32 + c;
      const u16* gb = Btile + (size_t)r * K + (t + 1) * 32 + c;
      u16* lb = lds[cur ^ 1];
      gload16(ga, lb + w * 512);
      gload16(ga + (size_t)64 * K, lb + 2048 + w * 512);
      gload16(gb, lb + 4096 + w * 512);
      gload16(gb + (size_t)64 * K, lb + 4096 + 2048 + w * 512);
    }
    const u16* lA = lds[cur];
    const u16* lB = lds[cur] + 4096;
    bf16x8 af[4], bfv[4];
#pragma unroll
    for (int mi = 0; mi < 4; ++mi)
      af[mi] = *reinterpret_cast<const bf16x8*>(
          lA + (wm + mi * 16 + (lane & 15)) * 32 + (lane >> 4) * 8);
#pragma unroll
    for (int ni = 0; ni < 4; ++ni)
      bfv[ni] = *reinterpret_cast<const bf16x8*>(
          lB + (wn + ni * 16 + (lane & 15)) * 32 + (lane >> 4) * 8);
#pragma unroll
    for (int mi = 0; mi < 4; ++mi)
#pragma unroll
      for (int ni = 0; ni < 4; ++ni)
        acc[mi][ni] = __builtin_amdgcn_mfma_f32_16x16x32_bf16(af[mi], bfv[ni],
                                                              acc[mi][ni], 0, 0, 0);
    cur ^= 1;
  }
  // epilogue
#pragma unroll
  for (int mi = 0; mi < 4; ++mi) {
#pragma unroll
    for (int ni = 0; ni < 4; ++ni) {
      int colg = n0 + wn + ni * 16 + (lane & 15);
      float bv = bias[colg];
#pragma unroll
      for (int rr = 0; rr < 4; ++rr) {
        int rowg = m0 + wm + mi * 16 + ((lane >> 4) << 2) + rr;
        float v = acc[mi][ni][rr] + bv;
        if (MODE == 1) {
          Cf[(size_t)rowg * N + colg] = v;
        } else {
          if (colg < D_MODEL) {
            // Q: fold softmax scale*log2e here (saves a mul/score in flash)
            u16 b = f2bf(v * 0.1803368801111f);
            int hh = colg >> 6, dd = colg & 63;
            Qd[((size_t)hh * S_LEN + rowg) * 64 + swz(rowg, dd)] = b;
          } else if (colg < 2 * D_MODEL) {
            u16 b = f2bf(v);
            int cc = colg - D_MODEL;
            int hh = cc >> 6, dd = cc & 63;
            Kd[((size_t)hh * S_LEN + rowg) * 64 + swz(rowg, dd)] = b;
          } else {
            u16 b = f2bf(v);
            int cc = colg - 2 * D_MODEL;
            int hh = cc >> 6, dd = cc & 63;
            int csl = sigma64(rowg & 63);  // sigma-permute kv within 64-tile
            Vtd[((size_t)hh * 64 + dd) * S_LEN + (rowg & ~63) + swz(dd, csl)] = b;
          }
        }
      }
    }
  }
}

// ---------------- bf16 GEMM, BM=128 x BN=64 (occupancy variant for proj) -----
// fp32 output + bias. Grid (N/64, M/128) -> 512 blocks at N=1024 (2/CU).
__global__ __launch_bounds__(256) void k_gemm_n64(
    const u16* __restrict__ A, const u16* __restrict__ Bt,
    const float* __restrict__ bias, float* __restrict__ Cf,
    int M, int N, int K) {
  __shared__ __align__(16) u16 lds[2][(128 + 64) * 32];
  const int tid = threadIdx.x;
  const int w = tid >> 6, lane = tid & 63;
  const int g = lane >> 4, ql = lane & 15;
  const int m0 = blockIdx.y * 128, n0 = blockIdx.x * 64;
  const u16* Atile = A + (size_t)m0 * K;
  const u16* Btile = Bt + (size_t)n0 * K;
  const int r = tid >> 2, c = (tid & 3) * 8;
  const int wm = (w >> 1) * 64, wn = (w & 1) * 32;

  f32x4 acc[4][2] = {};
  const int NT = K / 32;

  {  // stage tile 0: A rows r, r+64; B rows r
    const u16* ga = Atile + (size_t)r * K + c;
    const u16* gb = Btile + (size_t)r * K + c;
    u16* lb = lds[0];
    gload16(ga, lb + w * 512);
    gload16(ga + (size_t)64 * K, lb + 2048 + w * 512);
    gload16(gb, lb + 4096 + w * 512);
  }
  int cur = 0;
  for (int t = 0; t < NT; ++t) {
    __syncthreads();
    if (t + 1 < NT) {
      const u16* ga = Atile + (size_t)r * K + (t + 1) * 32 + c;
      const u16* gb = Btile + (size_t)r * K + (t + 1) * 32 + c;
      u16* lb = lds[cur ^ 1];
      gload16(ga, lb + w * 512);
      gload16(ga + (size_t)64 * K, lb + 2048 + w * 512);
      gload16(gb, lb + 4096 + w * 512);
    }
    const u16* lA = lds[cur];
    const u16* lB = lds[cur] + 4096;
    bf16x8 af[4], bfv[2];
#pragma unroll
    for (int mi = 0; mi < 4; ++mi)
      af[mi] = *reinterpret_cast<const bf16x8*>(
          lA + (wm + mi * 16 + ql) * 32 + g * 8);
#pragma unroll
    for (int ni = 0; ni < 2; ++ni)
      bfv[ni] = *reinterpret_cast<const bf16x8*>(
          lB + (wn + ni * 16 + ql) * 32 + g * 8);
#pragma unroll
    for (int mi = 0; mi < 4; ++mi)
#pragma unroll
      for (int ni = 0; ni < 2; ++ni)
        acc[mi][ni] = __builtin_amdgcn_mfma_f32_16x16x32_bf16(af[mi], bfv[ni],
                                                              acc[mi][ni], 0, 0, 0);
    cur ^= 1;
  }
#pragma unroll
  for (int mi = 0; mi < 4; ++mi)
#pragma unroll
    for (int ni = 0; ni < 2; ++ni) {
      int colg = n0 + wn + ni * 16 + ql;
      float bv = bias[colg];
#pragma unroll
      for (int rr = 0; rr < 4; ++rr) {
        int rowg = m0 + wm + mi * 16 + g * 4 + rr;
        Cf[(size_t)rowg * N + colg] = acc[mi][ni][rr] + bv;
      }
    }
}

// ---------------- flash attention: one KV-tile step for one Q-tile ----------
__device__ __forceinline__ void flash_tile(const u16* __restrict__ Ksb,
                                           const u16* __restrict__ Vsb,
                                           bf16x8 qa0, bf16x8 qa1,
                                           float& m_run, float& l_part,
                                           f32x4* oacc, int g, int ql, int qoff,
                                           bool diag) {
  // S^T = K Q^T : lane holds P[q][kv=16ni+4g+rr] (exp2 domain, Q pre-scaled)
  f32x4 sacc[4] = {};
#pragma unroll
  for (int kk = 0; kk < 2; ++kk) {
    bf16x8 qk = kk ? qa1 : qa0;
#pragma unroll
    for (int ni = 0; ni < 4; ++ni) {
      const int kvl = ni * 16 + ql;
      bf16x8 kb = *reinterpret_cast<const bf16x8*>(
          Ksb + kvl * 64 + swz(kvl, kk * 32 + g * 8));
      sacc[ni] = __builtin_amdgcn_mfma_f32_16x16x32_bf16(kb, qk, sacc[ni], 0, 0, 0);
    }
  }
  float pvv[4][4];
#pragma unroll
  for (int ni = 0; ni < 4; ++ni)
#pragma unroll
    for (int rr = 0; rr < 4; ++rr) pvv[ni][rr] = sacc[ni][rr];

  if (diag) {  // causal mask within the diagonal tile
#pragma unroll
    for (int ni = 0; ni < 4; ++ni)
#pragma unroll
      for (int rr = 0; rr < 4; ++rr)
        if (ni * 16 + g * 4 + rr > qoff) pvv[ni][rr] = -1e30f;
  }

  // row max: local over lane's 16 kv + 2-step cross-group combine
  float mx;
  {
    float a0 = fmaxf(fmaxf(pvv[0][0], pvv[0][1]), fmaxf(pvv[0][2], pvv[0][3]));
    float a1 = fmaxf(fmaxf(pvv[1][0], pvv[1][1]), fmaxf(pvv[1][2], pvv[1][3]));
    float a2 = fmaxf(fmaxf(pvv[2][0], pvv[2][1]), fmaxf(pvv[2][2], pvv[2][3]));
    float a3 = fmaxf(fmaxf(pvv[3][0], pvv[3][1]), fmaxf(pvv[3][2], pvv[3][3]));
    mx = fmaxf(fmaxf(a0, a1), fmaxf(a2, a3));
    mx = fmaxf(mx, __shfl_xor(mx, 16));
    mx = fmaxf(mx, __shfl_xor(mx, 32));
  }

  // defer-max: rescale only if some row's max grew by > 8 (wave-uniform)
  if (__any(mx > m_run + 8.f)) {
    float mn = fmaxf(m_run, mx);
    float alpha = exp2f(m_run - mn);
    m_run = mn;
    l_part *= alpha;
    float ao[4];
#pragma unroll
    for (int rr = 0; rr < 4; ++rr) ao[rr] = __shfl(alpha, g * 4 + rr);
#pragma unroll
    for (int ni = 0; ni < 4; ++ni)
#pragma unroll
      for (int rr = 0; rr < 4; ++rr) oacc[ni][rr] *= ao[rr];
  }

  // P = exp2(S - m); per-lane partial l; pack to bf16 A-fragments locally
  u32 pk[4][2];
  {
    float rs = 0.f;
#pragma unroll
    for (int ni = 0; ni < 4; ++ni) {
      float p0 = exp2f(pvv[ni][0] - m_run);
      float p1 = exp2f(pvv[ni][1] - m_run);
      float p2 = exp2f(pvv[ni][2] - m_run);
      float p3 = exp2f(pvv[ni][3] - m_run);
      rs += (p0 + p1) + (p2 + p3);
      pk[ni][0] = cvt_pk_bf16(p0, p1);
      pk[ni][1] = cvt_pk_bf16(p2, p3);
    }
    l_part += rs;
  }

  // O += P V  (pa local; vb plain b128 thanks to sigma-permuted V layout)
#pragma unroll
  for (int kk2 = 0; kk2 < 2; ++kk2) {
    u32x4 pw = {pk[2 * kk2][0], pk[2 * kk2][1], pk[2 * kk2 + 1][0], pk[2 * kk2 + 1][1]};
    bf16x8 pa = __builtin_bit_cast(bf16x8, pw);
#pragma unroll
    for (int ni = 0; ni < 4; ++ni) {
      const int dd = ni * 16 + ql;
      bf16x8 vb = *reinterpret_cast<const bf16x8*>(
          Vsb + dd * 64 + swz(dd, kk2 * 32 + g * 8));
      oacc[ni] = __builtin_amdgcn_mfma_f32_16x16x32_bf16(pa, vb, oacc[ni], 0, 0, 0);
    }
  }
}

// ---------------- flash attention (causal), interleaved Q-tile pairs --------
// Grid 512: block (i,h) handles Q-tiles A=63-i AND B=i with a SHARED KV stream.
// Phase 1 (j=0..i): both tiles compute on the staged tile (straight-line dual
// code -> ILP). Phase 2 (j=i+1..63-i): tile A only. Every block = exactly 65
// tile-computes -> uniform makespan, zero drain. LDS 32KB.
__global__ __launch_bounds__(256) void k_flash(const u16* __restrict__ Qd,
                                               const u16* __restrict__ Kd,
                                               const u16* __restrict__ Vtd,
                                               u16* __restrict__ Ao) {
  __shared__ __align__(16) u16 Ks[2][64 * 64];
  __shared__ __align__(16) u16 Vs[2][64 * 64];
  const int tid = threadIdx.x, w = tid >> 6, lane = tid & 63;
  const int bid = blockIdx.x;
  const int i = bid >> 4, h = bid & 15;  // i in [0,32)
  const int J = 63 - i;                  // tile A = J (long), tile B = i (short)
  const u16* Qh = Qd + (size_t)h * S_LEN * 64;
  const u16* Kh = Kd + (size_t)h * S_LEN * 64;
  const u16* Vh = Vtd + (size_t)h * 64 * S_LEN;
  const int r8 = tid >> 3, c8 = (tid & 7) * 8;
  const int g = lane >> 4, ql = lane & 15;
  const int qoff = w * 16 + ql;

  {  // prologue: stage K/V tile 0
    const u16* gk = Kh + (size_t)r8 * 64 + c8;
    gload16(gk, Ks[0] + w * 512);
    gload16(gk + 32 * 64, Ks[0] + 2048 + w * 512);
    const u16* gv = Vh + (size_t)r8 * S_LEN + c8;
    gload16(gv, Vs[0] + w * 512);
    gload16(gv + (size_t)32 * S_LEN, Vs[0] + 2048 + w * 512);
  }

  // Q fragments for both tiles: direct global->reg (pre-swizzled, pre-scaled)
  bf16x8 qaA[2], qaB[2];
  {
    const int rqA = J * 64 + w * 16 + ql;
    const int rqB = i * 64 + w * 16 + ql;
#pragma unroll
    for (int kk = 0; kk < 2; ++kk) {
      qaA[kk] = *reinterpret_cast<const bf16x8*>(
          Qh + (size_t)rqA * 64 + swz(rqA, kk * 32 + g * 8));
      qaB[kk] = *reinterpret_cast<const bf16x8*>(
          Qh + (size_t)rqB * 64 + swz(rqB, kk * 32 + g * 8));
    }
  }

  float mA = -1e30f, lA = 0.f, mB = -1e30f, lB = 0.f;
  f32x4 oA[4] = {}, oB[4] = {};

  __syncthreads();  // K/V tile 0 landed

  int cur = 0;
  // phase 1: j = 0..i -- both tiles active (dual straight-line -> ILP)
  for (int j = 0; j <= i; ++j) {
    {  // stage j+1 (j+1 <= i+1 <= J always in phase 1)
      const u16* gk = Kh + ((size_t)((j + 1) * 64 + r8)) * 64 + c8;
      gload16(gk, Ks[cur ^ 1] + w * 512);
      gload16(gk + 32 * 64, Ks[cur ^ 1] + 2048 + w * 512);
      const u16* gv = Vh + (size_t)r8 * S_LEN + (j + 1) * 64 + c8;
      gload16(gv, Vs[cur ^ 1] + w * 512);
      gload16(gv + (size_t)32 * S_LEN, Vs[cur ^ 1] + 2048 + w * 512);
    }
    flash_tile(Ks[cur], Vs[cur], qaA[0], qaA[1], mA, lA, oA, g, ql, qoff, false);
    flash_tile(Ks[cur], Vs[cur], qaB[0], qaB[1], mB, lB, oB, g, ql, qoff, j == i);
    __syncthreads();
    cur ^= 1;
  }
  // phase 2: j = i+1..J -- tile A only
  for (int j = i + 1; j <= J; ++j) {
    if (j < J) {
      const u16* gk = Kh + ((size_t)((j + 1) * 64 + r8)) * 64 + c8;
      gload16(gk, Ks[cur ^ 1] + w * 512);
      gload16(gk + 32 * 64, Ks[cur ^ 1] + 2048 + w * 512);
      const u16* gv = Vh + (size_t)r8 * S_LEN + (j + 1) * 64 + c8;
      gload16(gv, Vs[cur ^ 1] + w * 512);
      gload16(gv + (size_t)32 * S_LEN, Vs[cur ^ 1] + 2048 + w * 512);
    }
    flash_tile(Ks[cur], Vs[cur], qaA[0], qaA[1], mA, lA, oA, g, ql, qoff, j == J);
    __syncthreads();
    cur ^= 1;
  }

  // epilogue: reduce l, redistribute to oacc rows, write O (both tiles)
#pragma unroll
  for (int t = 0; t < 2; ++t) {
    float l = t ? lB : lA;
    f32x4* oacc = t ? oB : oA;
    int qt = t ? i : J;
    l += __shfl_xor(l, 16);
    l += __shfl_xor(l, 32);
    float inv = 1.f / l;
    float io[4];
#pragma unroll
    for (int rr = 0; rr < 4; ++rr) io[rr] = __shfl(inv, g * 4 + rr);
#pragma unroll
    for (int rr = 0; rr < 4; ++rr) {
      int rowg = qt * 64 + w * 16 + g * 4 + rr;
#pragma unroll
      for (int ni = 0; ni < 4; ++ni) {
        int colg = h * 64 + ni * 16 + ql;
        Ao[(size_t)rowg * D_MODEL + colg] = f2bf(oacc[ni][rr] * io[rr]);
      }
    }
  }
}

extern "C" void kernel_launch(void* const* d_in, const int* in_sizes, int n_in,
                              void* d_out, int out_size, void* d_ws, size_t ws_size,
                              hipStream_t stream) {
  const float* x = (const float*)d_in[0];
  const float* Wqkv = (const float*)d_in[1];
  const float* bqkv = (const float*)d_in[2];
  const float* Wproj = (const float*)d_in[3];
  const float* bproj = (const float*)d_in[4];
  float* out = (float*)d_out;
  char* ws = (char*)d_ws;

  // Workspace map (40 MB total; aout aliases xb, which is dead after k_gemm<0>):
  u16* xb = (u16*)(ws);                            // [0,8) MB   x as bf16
  u16* aout = (u16*)(ws);                          // [0,8) MB   attn out (reuses xb)
  u16* wqkvt = (u16*)(ws + (size_t)(8 << 20));     // [8,14) MB  Wqkv^T bf16
  u16* wprojt = (u16*)(ws + (size_t)(14 << 20));   // [14,16) MB Wproj^T bf16
  u16* Qd = (u16*)(ws + (size_t)(16 << 20));       // [16,24) MB
  u16* Kd = (u16*)(ws + (size_t)(24 << 20));       // [24,32) MB
  u16* Vtd = (u16*)(ws + (size_t)(32 << 20));      // [32,40) MB

  if (ws_size < (size_t)(40 << 20)) return;  // refuse to scribble OOB

  k_conv<<<dim3(4096), dim3(256), 0, stream>>>(x, xb, S_LEN * D_MODEL);
  k_transpose_conv<<<dim3(96, 32), dim3(32, 8), 0, stream>>>(Wqkv, wqkvt, D_MODEL,
                                                             3 * D_MODEL);
  k_transpose_conv<<<dim3(32, 32), dim3(32, 8), 0, stream>>>(Wproj, wprojt, D_MODEL,
                                                             D_MODEL);
  k_gemm<0><<<dim3(24, 32), dim3(256), 0, stream>>>(xb, wqkvt, bqkv, nullptr, Qd, Kd,
                                                    Vtd, S_LEN, 3 * D_MODEL, D_MODEL);
  k_flash<<<dim3(512), dim3(256), 0, stream>>>(Qd, Kd, Vtd, aout);
  k_gemm_n64<<<dim3(16, 32), dim3(256), 0, stream>>>(aout, wprojt, bproj, out, S_LEN,
                                                     D_MODEL, D_MODEL);
}